// Round 2
// baseline (245.050 us; speedup 1.0000x reference)
//
#include <hip/hip_runtime.h>
#include <math.h>

#define NNODES 50000
#define KNEI 16

// ---------------------------------------------------------------------------
// Prep: Wc (128 x 256) = [ W_top - W_bot | W_bot ]   (W is (256,128) row-major)
// Wc[k][j] : j<128 -> W[k][j] - W[k+128][j] ; j>=128 -> W[k+128][j-128]
// ---------------------------------------------------------------------------
__global__ __launch_bounds__(256) void prep_wc(const float* __restrict__ W,
                                               float* __restrict__ Wc) {
    int i = blockIdx.x * 256 + threadIdx.x;   // 0..32767
    int k = i >> 8;
    int j = i & 255;
    float v;
    if (j < 128)
        v = W[k * 128 + j] - W[(k + 128) * 128 + j];
    else
        v = W[(k + 128) * 128 + (j - 128)];
    Wc[i] = v;
}

// ---------------------------------------------------------------------------
// GEMM: R = x (50000x128) @ Wc (128x256).  Cols 0..127 -> P (+bias) into d_out,
// cols 128..255 -> Q into workspace.  Tile 64 rows x 256 cols, 256 threads,
// 8x8 register tile per thread, K=128 staged once in LDS.
// ---------------------------------------------------------------------------
__global__ __launch_bounds__(256) void gemm_pq(const float* __restrict__ x,
                                               const float* __restrict__ Wc,
                                               const float* __restrict__ bias,
                                               float* __restrict__ P,
                                               float* __restrict__ Q) {
    __shared__ float As[64][128];
    const int row0 = blockIdx.x * 64;
    const int t = threadIdx.x;

    // stage A tile: 64x128 floats = 2048 float4, coalesced
    #pragma unroll
    for (int i = 0; i < 8; ++i) {
        int f  = t + i * 256;
        int r  = f >> 5;
        int c4 = f & 31;
        int gr = row0 + r;
        float4 v = make_float4(0.f, 0.f, 0.f, 0.f);
        if (gr < NNODES) v = ((const float4*)x)[gr * 32 + c4];
        *(float4*)&As[r][c4 * 4] = v;
    }
    __syncthreads();

    const int rg   = t >> 5;   // 0..7  : row group (8 rows each)
    const int cg   = t & 31;   // 0..31 : col group (8 cols each)
    const int col0 = cg * 8;

    float acc[8][8];
    #pragma unroll
    for (int r = 0; r < 8; ++r)
        #pragma unroll
        for (int c = 0; c < 8; ++c) acc[r][c] = 0.f;

    #pragma unroll 2
    for (int k = 0; k < 128; k += 4) {
        float4 a[8];
        #pragma unroll
        for (int r = 0; r < 8; ++r)
            a[r] = *(const float4*)&As[rg * 8 + r][k];   // broadcast, conflict-free

        float4 b[4][2];
        #pragma unroll
        for (int kk = 0; kk < 4; ++kk) {
            b[kk][0] = *(const float4*)&Wc[(k + kk) * 256 + col0];
            b[kk][1] = *(const float4*)&Wc[(k + kk) * 256 + col0 + 4];
        }

        #pragma unroll
        for (int r = 0; r < 8; ++r) {
            const float* ap = (const float*)&a[r];
            #pragma unroll
            for (int kk = 0; kk < 4; ++kk) {
                float av = ap[kk];
                const float* bp = (const float*)&b[kk][0];  // 8 contiguous floats
                #pragma unroll
                for (int c = 0; c < 8; ++c) acc[r][c] += av * bp[c];
            }
        }
    }

    // epilogue
    if (cg < 16) {
        float4 bb0 = *(const float4*)&bias[col0];
        float4 bb1 = *(const float4*)&bias[col0 + 4];
        #pragma unroll
        for (int r = 0; r < 8; ++r) {
            int row = row0 + rg * 8 + r;
            if (row < NNODES) {
                float4 v0 = make_float4(acc[r][0] + bb0.x, acc[r][1] + bb0.y,
                                        acc[r][2] + bb0.z, acc[r][3] + bb0.w);
                float4 v1 = make_float4(acc[r][4] + bb1.x, acc[r][5] + bb1.y,
                                        acc[r][6] + bb1.z, acc[r][7] + bb1.w);
                *(float4*)&P[row * 128 + col0]     = v0;
                *(float4*)&P[row * 128 + col0 + 4] = v1;
            }
        }
    } else {
        const int qcol = col0 - 128;
        #pragma unroll
        for (int r = 0; r < 8; ++r) {
            int row = row0 + rg * 8 + r;
            if (row < NNODES) {
                float4 v0 = make_float4(acc[r][0], acc[r][1], acc[r][2], acc[r][3]);
                float4 v1 = make_float4(acc[r][4], acc[r][5], acc[r][6], acc[r][7]);
                *(float4*)&Q[row * 128 + qcol]     = v0;
                *(float4*)&Q[row * 128 + qcol + 4] = v1;
            }
        }
    }
}

// ---------------------------------------------------------------------------
// Gather + ELU + masked max.  2 nodes per 256-thread block, thread o in 0..127.
// out[n,o] = max over valid k of elu(P[n,o] + Q[edge[n,k],o]).
// P aliases out (each thread reads its own element before writing it).
// ---------------------------------------------------------------------------
__global__ __launch_bounds__(256) void gather_max(const float* P,
                                                  const float* __restrict__ Q,
                                                  const int* __restrict__ edge,
                                                  float* out) {
    const int t = threadIdx.x;
    const int n = blockIdx.x * 2 + (t >> 7);
    const int o = t & 127;

    float p = P[n * 128 + o];

    // 16 edge indices for this node (64B, broadcast within wave)
    const int4* erow = (const int4*)(edge + n * KNEI);
    int4 e0 = erow[0], e1 = erow[1], e2 = erow[2], e3 = erow[3];
    int e[16] = {e0.x, e0.y, e0.z, e0.w, e1.x, e1.y, e1.z, e1.w,
                 e2.x, e2.y, e2.z, e2.w, e3.x, e3.y, e3.z, e3.w};

    float m = -INFINITY;
    #pragma unroll
    for (int k = 0; k < KNEI; ++k) {
        int ek = e[k];
        int idx = ek < 0 ? 0 : ek;                 // safe dummy row for masked edges
        float q = Q[(size_t)idx * 128 + o];
        float z = p + q;
        float v = z > 0.f ? z : expm1f(z);
        if (ek >= 0) m = fmaxf(m, v);
    }
    out[n * 128 + o] = m;
}

extern "C" void kernel_launch(void* const* d_in, const int* in_sizes, int n_in,
                              void* d_out, int out_size, void* d_ws, size_t ws_size,
                              hipStream_t stream) {
    const float* x    = (const float*)d_in[0];
    const int*   edge = (const int*)d_in[1];
    const float* W    = (const float*)d_in[2];
    const float* bias = (const float*)d_in[3];
    float* out = (float*)d_out;

    float* Wc = (float*)d_ws;            // 128*256 floats = 128 KB
    float* Q  = (float*)d_ws + 32768;    // 50000*128 floats = 25.6 MB

    prep_wc<<<128, 256, 0, stream>>>(W, Wc);
    gemm_pq<<<(NNODES + 63) / 64, 256, 0, stream>>>(x, Wc, bias, out, Q);
    gather_max<<<NNODES / 2, 256, 0, stream>>>(out, Q, edge, out);
}

// Round 3
// 205.537 us; speedup vs baseline: 1.1922x; 1.1922x over previous
//
#include <hip/hip_runtime.h>
#include <math.h>

#define NNODES 50000
#define KNEI 16

// ---------------------------------------------------------------------------
// Prep: Wc (128 x 256) = [ W_top - W_bot | W_bot ]   (W is (256,128) row-major)
// ---------------------------------------------------------------------------
__global__ __launch_bounds__(256) void prep_wc(const float* __restrict__ W,
                                               float* __restrict__ Wc) {
    int i = blockIdx.x * 256 + threadIdx.x;   // 0..32767
    int k = i >> 8;
    int j = i & 255;
    float v;
    if (j < 128)
        v = W[k * 128 + j] - W[(k + 128) * 128 + j];
    else
        v = W[(k + 128) * 128 + (j - 128)];
    Wc[i] = v;
}

// ---------------------------------------------------------------------------
// GEMM: R = x (50000x128) @ Wc (128x256).  Cols 0..127 -> P (+bias) -> d_out,
// cols 128..255 -> Q -> workspace.  64x256 tile, 256 threads, 8x8 reg tile.
// Low-pressure variant: per-k scalar A broadcast + JIT float4 B loads.
// ---------------------------------------------------------------------------
__global__ __launch_bounds__(256) void gemm_pq(const float* __restrict__ x,
                                               const float* __restrict__ Wc,
                                               const float* __restrict__ bias,
                                               float* __restrict__ P,
                                               float* __restrict__ Q) {
    __shared__ float As[64][128];
    const int row0 = blockIdx.x * 64;
    const int t = threadIdx.x;

    // stage A tile: 64x128 floats = 2048 float4, coalesced
    #pragma unroll
    for (int i = 0; i < 8; ++i) {
        int f  = t + i * 256;
        int r  = f >> 5;
        int c4 = f & 31;
        int gr = row0 + r;
        float4 v = make_float4(0.f, 0.f, 0.f, 0.f);
        if (gr < NNODES) v = ((const float4*)x)[gr * 32 + c4];
        *(float4*)&As[r][c4 * 4] = v;
    }
    __syncthreads();

    const int rg   = t >> 5;   // 0..7  : row group (8 rows each)
    const int cg   = t & 31;   // 0..31 : col group (8 cols each)
    const int col0 = cg * 8;
    const float* wp = Wc + col0;

    float acc[8][8];
    #pragma unroll
    for (int r = 0; r < 8; ++r)
        #pragma unroll
        for (int c = 0; c < 8; ++c) acc[r][c] = 0.f;

    #pragma unroll 4
    for (int k = 0; k < 128; ++k) {
        float4 b0 = *(const float4*)&wp[k * 256];
        float4 b1 = *(const float4*)&wp[k * 256 + 4];
        float a[8];
        #pragma unroll
        for (int r = 0; r < 8; ++r) a[r] = As[rg * 8 + r][k];  // broadcast read
        #pragma unroll
        for (int r = 0; r < 8; ++r) {
            acc[r][0] += a[r] * b0.x;
            acc[r][1] += a[r] * b0.y;
            acc[r][2] += a[r] * b0.z;
            acc[r][3] += a[r] * b0.w;
            acc[r][4] += a[r] * b1.x;
            acc[r][5] += a[r] * b1.y;
            acc[r][6] += a[r] * b1.z;
            acc[r][7] += a[r] * b1.w;
        }
    }

    // epilogue
    if (cg < 16) {
        float4 bb0 = *(const float4*)&bias[col0];
        float4 bb1 = *(const float4*)&bias[col0 + 4];
        #pragma unroll
        for (int r = 0; r < 8; ++r) {
            int row = row0 + rg * 8 + r;
            if (row < NNODES) {
                float4 v0 = make_float4(acc[r][0] + bb0.x, acc[r][1] + bb0.y,
                                        acc[r][2] + bb0.z, acc[r][3] + bb0.w);
                float4 v1 = make_float4(acc[r][4] + bb1.x, acc[r][5] + bb1.y,
                                        acc[r][6] + bb1.z, acc[r][7] + bb1.w);
                *(float4*)&P[row * 128 + col0]     = v0;
                *(float4*)&P[row * 128 + col0 + 4] = v1;
            }
        }
    } else {
        const int qcol = col0 - 128;
        #pragma unroll
        for (int r = 0; r < 8; ++r) {
            int row = row0 + rg * 8 + r;
            if (row < NNODES) {
                float4 v0 = make_float4(acc[r][0], acc[r][1], acc[r][2], acc[r][3]);
                float4 v1 = make_float4(acc[r][4], acc[r][5], acc[r][6], acc[r][7]);
                *(float4*)&Q[row * 128 + qcol]     = v0;
                *(float4*)&Q[row * 128 + qcol + 4] = v1;
            }
        }
    }
}

// ---------------------------------------------------------------------------
// Gather + masked max + single ELU.
// ELU is strictly monotone:  max_k elu(p + q_k) = elu(p + max_k q_k).
// 8 nodes per 256-thread block; 32 threads/node; each thread owns 4 floats.
// k=0 is never masked, so init with it.  P aliases out (private elements).
// ---------------------------------------------------------------------------
__global__ __launch_bounds__(256) void gather_max(const float* __restrict__ P,
                                                  const float* __restrict__ Q,
                                                  const int* __restrict__ edge,
                                                  float* __restrict__ out) {
    const int t = threadIdx.x;
    const int n = blockIdx.x * 8 + (t >> 5);   // 50000 = 8 * 6250, exact
    const int o = (t & 31) * 4;

    const int4* erow = (const int4*)(edge + n * KNEI);
    int4 e0 = erow[0], e1 = erow[1], e2 = erow[2], e3 = erow[3];
    int e[16] = {e0.x, e0.y, e0.z, e0.w, e1.x, e1.y, e1.z, e1.w,
                 e2.x, e2.y, e2.z, e2.w, e3.x, e3.y, e3.z, e3.w};

    // k = 0 always valid
    float4 m = *(const float4*)&Q[(size_t)e[0] * 128 + o];
    #pragma unroll
    for (int k = 1; k < KNEI; ++k) {
        int ek  = e[k];
        int idx = ek < 0 ? e[0] : ek;          // keep load unconditional
        float4 q = *(const float4*)&Q[(size_t)idx * 128 + o];
        if (ek >= 0) {
            m.x = fmaxf(m.x, q.x);
            m.y = fmaxf(m.y, q.y);
            m.z = fmaxf(m.z, q.z);
            m.w = fmaxf(m.w, q.w);
        }
    }
    float4 p = *(const float4*)&P[n * 128 + o];
    float4 z = make_float4(p.x + m.x, p.y + m.y, p.z + m.z, p.w + m.w);
    float4 r;
    r.x = z.x > 0.f ? z.x : expm1f(z.x);
    r.y = z.y > 0.f ? z.y : expm1f(z.y);
    r.z = z.z > 0.f ? z.z : expm1f(z.z);
    r.w = z.w > 0.f ? z.w : expm1f(z.w);
    *(float4*)&out[n * 128 + o] = r;
}

extern "C" void kernel_launch(void* const* d_in, const int* in_sizes, int n_in,
                              void* d_out, int out_size, void* d_ws, size_t ws_size,
                              hipStream_t stream) {
    const float* x    = (const float*)d_in[0];
    const int*   edge = (const int*)d_in[1];
    const float* W    = (const float*)d_in[2];
    const float* bias = (const float*)d_in[3];
    float* out = (float*)d_out;

    float* Wc = (float*)d_ws;            // 128*256 floats = 128 KB
    float* Q  = (float*)d_ws + 32768;    // 50000*128 floats = 25.6 MB

    prep_wc<<<128, 256, 0, stream>>>(W, Wc);
    gemm_pq<<<(NNODES + 63) / 64, 256, 0, stream>>>(x, Wc, bias, out, Q);
    gather_max<<<NNODES / 8, 256, 0, stream>>>(out, Q, edge, out);
}

// Round 4
// 200.407 us; speedup vs baseline: 1.2228x; 1.0256x over previous
//
#include <hip/hip_runtime.h>
#include <math.h>

#define NNODES 50000
#define KNEI 16

// ---------------------------------------------------------------------------
// Prep: Wc (128 x 256) = [ W_top - W_bot | W_bot ]   (W is (256,128) row-major)
// ---------------------------------------------------------------------------
__global__ __launch_bounds__(256) void prep_wc(const float* __restrict__ W,
                                               float* __restrict__ Wc) {
    int i = blockIdx.x * 256 + threadIdx.x;   // 0..32767
    int k = i >> 8;
    int j = i & 255;
    float v;
    if (j < 128)
        v = W[k * 128 + j] - W[(k + 128) * 128 + j];
    else
        v = W[(k + 128) * 128 + (j - 128)];
    Wc[i] = v;
}

// ---------------------------------------------------------------------------
// GEMM: R = x (50000x128) @ Wc (128x256).  Cols 0..127 -> P (+bias) -> d_out,
// cols 128..255 -> Q -> workspace.
// 64x256 tile, 512 threads (8 waves/block -> ~24 waves/CU), 4x8 reg tile.
// Low VGPR (~60) so occupancy is block-limited at 75%, not VGPR-limited.
// ---------------------------------------------------------------------------
__global__ __launch_bounds__(512) void gemm_pq(const float* __restrict__ x,
                                               const float* __restrict__ Wc,
                                               const float* __restrict__ bias,
                                               float* __restrict__ P,
                                               float* __restrict__ Q) {
    __shared__ float As[64][128];
    const int row0 = blockIdx.x * 64;
    const int t = threadIdx.x;

    // stage A tile: 64x128 floats = 2048 float4, coalesced, 4 per thread
    #pragma unroll
    for (int i = 0; i < 4; ++i) {
        int f  = t + i * 512;
        int r  = f >> 5;
        int c4 = f & 31;
        int gr = row0 + r;
        float4 v = make_float4(0.f, 0.f, 0.f, 0.f);
        if (gr < NNODES) v = ((const float4*)x)[gr * 32 + c4];
        *(float4*)&As[r][c4 * 4] = v;
    }
    __syncthreads();

    const int rg   = t >> 5;   // 0..15 : row group (4 rows each)
    const int cg   = t & 31;   // 0..31 : col group (8 cols each)
    const int col0 = cg * 8;
    const float* wp = Wc + col0;

    float acc[4][8];
    #pragma unroll
    for (int r = 0; r < 4; ++r)
        #pragma unroll
        for (int c = 0; c < 8; ++c) acc[r][c] = 0.f;

    #pragma unroll 4
    for (int k = 0; k < 128; ++k) {
        float4 b0 = *(const float4*)&wp[k * 256];
        float4 b1 = *(const float4*)&wp[k * 256 + 4];
        float a[4];
        #pragma unroll
        for (int r = 0; r < 4; ++r) a[r] = As[rg * 4 + r][k];  // broadcast read
        #pragma unroll
        for (int r = 0; r < 4; ++r) {
            acc[r][0] += a[r] * b0.x;
            acc[r][1] += a[r] * b0.y;
            acc[r][2] += a[r] * b0.z;
            acc[r][3] += a[r] * b0.w;
            acc[r][4] += a[r] * b1.x;
            acc[r][5] += a[r] * b1.y;
            acc[r][6] += a[r] * b1.z;
            acc[r][7] += a[r] * b1.w;
        }
    }

    // epilogue
    if (cg < 16) {
        float4 bb0 = *(const float4*)&bias[col0];
        float4 bb1 = *(const float4*)&bias[col0 + 4];
        #pragma unroll
        for (int r = 0; r < 4; ++r) {
            int row = row0 + rg * 4 + r;
            if (row < NNODES) {
                float4 v0 = make_float4(acc[r][0] + bb0.x, acc[r][1] + bb0.y,
                                        acc[r][2] + bb0.z, acc[r][3] + bb0.w);
                float4 v1 = make_float4(acc[r][4] + bb1.x, acc[r][5] + bb1.y,
                                        acc[r][6] + bb1.z, acc[r][7] + bb1.w);
                *(float4*)&P[row * 128 + col0]     = v0;
                *(float4*)&P[row * 128 + col0 + 4] = v1;
            }
        }
    } else {
        const int qcol = col0 - 128;
        #pragma unroll
        for (int r = 0; r < 4; ++r) {
            int row = row0 + rg * 4 + r;
            if (row < NNODES) {
                float4 v0 = make_float4(acc[r][0], acc[r][1], acc[r][2], acc[r][3]);
                float4 v1 = make_float4(acc[r][4], acc[r][5], acc[r][6], acc[r][7]);
                *(float4*)&Q[row * 128 + qcol]     = v0;
                *(float4*)&Q[row * 128 + qcol + 4] = v1;
            }
        }
    }
}

// ---------------------------------------------------------------------------
// Gather + masked max + single ELU.
// ELU is strictly monotone:  max_k elu(p + q_k) = elu(p + max_k q_k).
// 8 nodes per 256-thread block; 32 threads/node; each thread owns 4 floats.
// k=0 is never masked, so init with it.  P aliases out (private elements).
// ---------------------------------------------------------------------------
__global__ __launch_bounds__(256) void gather_max(const float* __restrict__ P,
                                                  const float* __restrict__ Q,
                                                  const int* __restrict__ edge,
                                                  float* __restrict__ out) {
    const int t = threadIdx.x;
    const int n = blockIdx.x * 8 + (t >> 5);   // 50000 = 8 * 6250, exact
    const int o = (t & 31) * 4;

    const int4* erow = (const int4*)(edge + n * KNEI);
    int4 e0 = erow[0], e1 = erow[1], e2 = erow[2], e3 = erow[3];
    int e[16] = {e0.x, e0.y, e0.z, e0.w, e1.x, e1.y, e1.z, e1.w,
                 e2.x, e2.y, e2.z, e2.w, e3.x, e3.y, e3.z, e3.w};

    // k = 0 always valid
    float4 m = *(const float4*)&Q[(size_t)e[0] * 128 + o];
    #pragma unroll
    for (int k = 1; k < KNEI; ++k) {
        int ek  = e[k];
        int idx = ek < 0 ? e[0] : ek;          // keep load unconditional
        float4 q = *(const float4*)&Q[(size_t)idx * 128 + o];
        if (ek >= 0) {
            m.x = fmaxf(m.x, q.x);
            m.y = fmaxf(m.y, q.y);
            m.z = fmaxf(m.z, q.z);
            m.w = fmaxf(m.w, q.w);
        }
    }
    float4 p = *(const float4*)&P[n * 128 + o];
    float4 z = make_float4(p.x + m.x, p.y + m.y, p.z + m.z, p.w + m.w);
    float4 r;
    r.x = z.x > 0.f ? z.x : expm1f(z.x);
    r.y = z.y > 0.f ? z.y : expm1f(z.y);
    r.z = z.z > 0.f ? z.z : expm1f(z.z);
    r.w = z.w > 0.f ? z.w : expm1f(z.w);
    *(float4*)&out[n * 128 + o] = r;
}

extern "C" void kernel_launch(void* const* d_in, const int* in_sizes, int n_in,
                              void* d_out, int out_size, void* d_ws, size_t ws_size,
                              hipStream_t stream) {
    const float* x    = (const float*)d_in[0];
    const int*   edge = (const int*)d_in[1];
    const float* W    = (const float*)d_in[2];
    const float* bias = (const float*)d_in[3];
    float* out = (float*)d_out;

    float* Wc = (float*)d_ws;            // 128*256 floats = 128 KB
    float* Q  = (float*)d_ws + 32768;    // 50000*128 floats = 25.6 MB

    prep_wc<<<128, 256, 0, stream>>>(W, Wc);
    gemm_pq<<<(NNODES + 63) / 64, 512, 0, stream>>>(x, Wc, bias, out, Q);
    gather_max<<<NNODES / 8, 256, 0, stream>>>(out, Q, edge, out);
}

// Round 5
// 154.519 us; speedup vs baseline: 1.5859x; 1.2970x over previous
//
#include <hip/hip_runtime.h>
#include <hip/hip_bf16.h>
#include <math.h>

#define NNODES 50000
#define KNEI 16

typedef __attribute__((ext_vector_type(8))) short bf8;
typedef __attribute__((ext_vector_type(4))) float f32x4;

static __device__ __forceinline__ unsigned short f2bf(float f) {
    __hip_bfloat16 h = __float2bfloat16(f);
    return *reinterpret_cast<unsigned short*>(&h);
}

// ---------------------------------------------------------------------------
// prep_bt: BT[c][k] = bf16(Wc[k][c]), c in 0..255, k in 0..127 (64 KB).
// Wc[k][c] = c<128 ? W[k][c] - W[k+128][c] : W[k+128][c-128]
// ---------------------------------------------------------------------------
__global__ __launch_bounds__(128) void prep_bt(const float* __restrict__ W,
                                               unsigned short* __restrict__ BT) {
    int c = blockIdx.x;      // 0..255
    int k = threadIdx.x;     // 0..127
    float v;
    if (c < 128) v = W[k * 128 + c] - W[(k + 128) * 128 + c];
    else         v = W[(k + 128) * 128 + (c - 128)];
    BT[c * 128 + k] = f2bf(v);
}

// ---------------------------------------------------------------------------
// gemm_bf16: R = x (50000x128) @ Wc (128x256) via mfma_f32_16x16x32_bf16.
// Block: 256 thr = 4 waves, tile 64 rows x 128 cols; grid (782, 2).
// blockIdx.y==0 -> P (=d_out, +bias) cols 0..127 ; ==1 -> Q cols 128..255.
// x tile staged fp32->bf16 into LDS [64][136] (pad 136: 2-way banks, 16B align).
// K=128 = 4 mfma k-steps, single stage, no double-buffer.
// Wave w: rows 0..63 (4 m-frags), cols w*32..w*32+31 (2 n-frags).
// ---------------------------------------------------------------------------
__global__ __launch_bounds__(256) void gemm_bf16(const float* __restrict__ x,
                                                 const unsigned short* __restrict__ BT,
                                                 const float* __restrict__ bias,
                                                 float* __restrict__ P,
                                                 float* __restrict__ Q) {
    __shared__ unsigned short As[64][136];
    const int t = threadIdx.x;
    const int row0 = blockIdx.x * 64;

    // stage + convert: 64x128 fp32 -> bf16, 8 float4 per thread
    #pragma unroll
    for (int i = 0; i < 8; ++i) {
        int f  = t + i * 256;          // 0..2047
        int r  = f >> 5;
        int c4 = f & 31;
        int gr = row0 + r;
        float4 v = make_float4(0.f, 0.f, 0.f, 0.f);
        if (gr < NNODES) v = ((const float4*)x)[gr * 32 + c4];
        unsigned int u0 = (unsigned int)f2bf(v.x) | ((unsigned int)f2bf(v.y) << 16);
        unsigned int u1 = (unsigned int)f2bf(v.z) | ((unsigned int)f2bf(v.w) << 16);
        *(uint2*)&As[r][c4 * 4] = make_uint2(u0, u1);
    }
    __syncthreads();

    const int w  = t >> 6;          // wave 0..3
    const int l  = t & 63;          // lane
    const int lr = l & 15;          // row/col within frag
    const int lk = (l >> 4) * 8;    // k-offset within frag
    const int ctile = blockIdx.y;   // 0:P 1:Q

    f32x4 acc[4][2];
    #pragma unroll
    for (int m = 0; m < 4; ++m)
        #pragma unroll
        for (int n = 0; n < 2; ++n) acc[m][n] = (f32x4){0.f, 0.f, 0.f, 0.f};

    const int colL0 = w * 32 + lr;              // local col of n-frag 0
    const unsigned short* bt0 = BT + (ctile * 128 + colL0) * 128 + lk;

    #pragma unroll
    for (int s = 0; s < 4; ++s) {
        const int kp = s * 32;
        bf8 a[4], b[2];
        #pragma unroll
        for (int m = 0; m < 4; ++m)
            a[m] = *(const bf8*)&As[m * 16 + lr][kp + lk];
        #pragma unroll
        for (int n = 0; n < 2; ++n)
            b[n] = *(const bf8*)(bt0 + n * 16 * 128 + kp);
        #pragma unroll
        for (int m = 0; m < 4; ++m)
            #pragma unroll
            for (int n = 0; n < 2; ++n)
                acc[m][n] = __builtin_amdgcn_mfma_f32_16x16x32_bf16(a[m], b[n], acc[m][n], 0, 0, 0);
    }

    // epilogue: D layout col=lane&15, row=(lane>>4)*4+reg (m89-verified)
    float bb[2];
    bb[0] = (ctile == 0) ? bias[colL0] : 0.f;
    bb[1] = (ctile == 0) ? bias[colL0 + 16] : 0.f;
    float* dst = (ctile == 0) ? P : Q;
    #pragma unroll
    for (int m = 0; m < 4; ++m) {
        #pragma unroll
        for (int n = 0; n < 2; ++n) {
            int colL = colL0 + n * 16;
            #pragma unroll
            for (int i = 0; i < 4; ++i) {
                int row = row0 + m * 16 + (l >> 4) * 4 + i;
                if (row < NNODES) dst[row * 128 + colL] = acc[m][n][i] + bb[n];
            }
        }
    }
}

// ---------------------------------------------------------------------------
// gather_max: out[n,o] = elu(P[n,o] + max_valid_k Q[edge[n,k],o])
// (ELU monotone -> max before activation). 8 nodes/block, 32 thr/node, 4 f/thr.
// All 16 gathers issued into distinct registers (MLP=16); masked k loads the
// always-valid e[0] row (idempotent under max). Pairwise fmax tree.
// ---------------------------------------------------------------------------
static __device__ __forceinline__ float4 fmax4(float4 a, float4 b) {
    return make_float4(fmaxf(a.x, b.x), fmaxf(a.y, b.y),
                       fmaxf(a.z, b.z), fmaxf(a.w, b.w));
}

__global__ __launch_bounds__(256) void gather_max(const float* __restrict__ P,
                                                  const float* __restrict__ Q,
                                                  const int* __restrict__ edge,
                                                  float* __restrict__ out) {
    const int t = threadIdx.x;
    const int n = blockIdx.x * 8 + (t >> 5);   // 50000 = 8 * 6250
    const int o = (t & 31) * 4;

    const int4* er = (const int4*)(edge + n * KNEI);
    int4 e0 = er[0], e1 = er[1], e2 = er[2], e3 = er[3];
    int ia[16] = {e0.x, e0.y, e0.z, e0.w, e1.x, e1.y, e1.z, e1.w,
                  e2.x, e2.y, e2.z, e2.w, e3.x, e3.y, e3.z, e3.w};
    const int s0 = ia[0];                      // k=0 never masked
    const float* qb = Q + o;

    float4 q[16];
    #pragma unroll
    for (int k = 0; k < 16; ++k) {
        int ix = ia[k] < 0 ? s0 : ia[k];
        q[k] = *(const float4*)&qb[(size_t)ix * 128];
    }
    float4 p = *(const float4*)&P[n * 128 + o];

    #pragma unroll
    for (int st = 8; st >= 1; st >>= 1)
        #pragma unroll
        for (int k = 0; k < st; ++k) q[k] = fmax4(q[k], q[k + st]);

    float4 z = make_float4(p.x + q[0].x, p.y + q[0].y, p.z + q[0].z, p.w + q[0].w);
    float4 r;
    r.x = z.x > 0.f ? z.x : expm1f(z.x);
    r.y = z.y > 0.f ? z.y : expm1f(z.y);
    r.z = z.z > 0.f ? z.z : expm1f(z.z);
    r.w = z.w > 0.f ? z.w : expm1f(z.w);
    *(float4*)&out[n * 128 + o] = r;
}

extern "C" void kernel_launch(void* const* d_in, const int* in_sizes, int n_in,
                              void* d_out, int out_size, void* d_ws, size_t ws_size,
                              hipStream_t stream) {
    const float* x    = (const float*)d_in[0];
    const int*   edge = (const int*)d_in[1];
    const float* W    = (const float*)d_in[2];
    const float* bias = (const float*)d_in[3];
    float* out = (float*)d_out;

    float*          Q  = (float*)d_ws;                          // 25,600,000 B
    unsigned short* BT = (unsigned short*)((char*)d_ws + 25600000);  // 65,536 B

    prep_bt<<<256, 128, 0, stream>>>(W, BT);
    gemm_bf16<<<dim3((NNODES + 63) / 64, 2), 256, 0, stream>>>(x, BT, bias, out, Q);
    gather_max<<<NNODES / 8, 256, 0, stream>>>(out, Q, edge, out);
}

// Round 8
// 122.278 us; speedup vs baseline: 2.0040x; 1.2637x over previous
//
#include <hip/hip_runtime.h>
#include <hip/hip_bf16.h>
#include <hip/hip_fp16.h>
#include <math.h>

#define NNODES 50000
#define KNEI 16

typedef __attribute__((ext_vector_type(8))) short bf8;
typedef __attribute__((ext_vector_type(4))) float f32x4;

static __device__ __forceinline__ unsigned short f2bf(float f) {
    __hip_bfloat16 h = __float2bfloat16(f);
    return *reinterpret_cast<unsigned short*>(&h);
}
static __device__ __forceinline__ unsigned short f2h(float f) {
    __half h = __float2half(f);
    return *reinterpret_cast<unsigned short*>(&h);
}
static __device__ __forceinline__ float2 h2f2(unsigned int u) {
    __half2 h = *reinterpret_cast<__half2*>(&u);
    return __half22float2(h);
}

// ---------------------------------------------------------------------------
// prep_bt: BT[c][k] = bf16(Wc[k][c]), c in 0..255, k in 0..127 (64 KB).
// Wc[k][c] = c<128 ? W[k][c] - W[k+128][c] : W[k+128][c-128]
// ---------------------------------------------------------------------------
__global__ __launch_bounds__(128) void prep_bt(const float* __restrict__ W,
                                               unsigned short* __restrict__ BT) {
    int c = blockIdx.x;      // 0..255
    int k = threadIdx.x;     // 0..127
    float v;
    if (c < 128) v = W[k * 128 + c] - W[(k + 128) * 128 + c];
    else         v = W[(k + 128) * 128 + (c - 128)];
    BT[c * 128 + k] = f2bf(v);
}

// ---------------------------------------------------------------------------
// gemm_bf16: R = x (50000x128) @ Wc (128x256) via mfma_f32_16x16x32_bf16.
// Grid (782, 2): blockIdx.y==0 -> Ph (+bias), ==1 -> Qh. Both stored fp16.
// Epilogue: fp32 acc (+bias) -> fp16 -> LDS repack (reusing As) ->
// coalesced uint4 (16 B) global stores.
// ---------------------------------------------------------------------------
__global__ __launch_bounds__(256) void gemm_bf16(const float* __restrict__ x,
                                                 const unsigned short* __restrict__ BT,
                                                 const float* __restrict__ bias,
                                                 unsigned short* __restrict__ Ph,
                                                 unsigned short* __restrict__ Qh) {
    __shared__ unsigned short As[64][136];
    const int t = threadIdx.x;
    const int row0 = blockIdx.x * 64;

    // stage + convert: 64x128 fp32 -> bf16, 8 float4 per thread
    #pragma unroll
    for (int i = 0; i < 8; ++i) {
        int f  = t + i * 256;          // 0..2047
        int r  = f >> 5;
        int c4 = f & 31;
        int gr = row0 + r;
        float4 v = make_float4(0.f, 0.f, 0.f, 0.f);
        if (gr < NNODES) v = ((const float4*)x)[gr * 32 + c4];
        unsigned int u0 = (unsigned int)f2bf(v.x) | ((unsigned int)f2bf(v.y) << 16);
        unsigned int u1 = (unsigned int)f2bf(v.z) | ((unsigned int)f2bf(v.w) << 16);
        *(uint2*)&As[r][c4 * 4] = make_uint2(u0, u1);
    }
    __syncthreads();

    const int w  = t >> 6;          // wave 0..3
    const int l  = t & 63;          // lane
    const int lr = l & 15;          // row/col within frag
    const int lk = (l >> 4) * 8;    // k-offset within frag
    const int ctile = blockIdx.y;   // 0:P 1:Q

    f32x4 acc[4][2];
    #pragma unroll
    for (int m = 0; m < 4; ++m)
        #pragma unroll
        for (int n = 0; n < 2; ++n) acc[m][n] = (f32x4){0.f, 0.f, 0.f, 0.f};

    const int colL0 = w * 32 + lr;              // local col of n-frag 0
    const unsigned short* bt0 = BT + (ctile * 128 + colL0) * 128 + lk;

    #pragma unroll
    for (int s = 0; s < 4; ++s) {
        const int kp = s * 32;
        bf8 a[4], b[2];
        #pragma unroll
        for (int m = 0; m < 4; ++m)
            a[m] = *(const bf8*)&As[m * 16 + lr][kp + lk];
        #pragma unroll
        for (int n = 0; n < 2; ++n)
            b[n] = *(const bf8*)(bt0 + n * 16 * 128 + kp);
        #pragma unroll
        for (int m = 0; m < 4; ++m)
            #pragma unroll
            for (int n = 0; n < 2; ++n)
                acc[m][n] = __builtin_amdgcn_mfma_f32_16x16x32_bf16(a[m], b[n], acc[m][n], 0, 0, 0);
    }

    // epilogue: D layout col=lane&15, row=(lane>>4)*4+reg (m89-verified)
    const float b0v = (ctile == 0) ? bias[colL0]      : 0.f;
    const float b1v = (ctile == 0) ? bias[colL0 + 16] : 0.f;
    unsigned short* dst = (ctile == 0) ? Ph : Qh;

    __syncthreads();                 // all As reads complete before reuse
    unsigned short* Ls = &As[0][0];  // repack buffer [64][136]
    #pragma unroll
    for (int m = 0; m < 4; ++m) {
        #pragma unroll
        for (int n = 0; n < 2; ++n) {
            int cl = colL0 + n * 16;
            float bb = n ? b1v : b0v;
            #pragma unroll
            for (int i = 0; i < 4; ++i) {
                int rl = m * 16 + (l >> 4) * 4 + i;
                Ls[rl * 136 + cl] = f2h(acc[m][n][i] + bb);
            }
        }
    }
    __syncthreads();

    #pragma unroll
    for (int it = 0; it < 4; ++it) {
        int cidx = t + it * 256;     // 0..1023
        int row  = cidx >> 4;
        int seg  = cidx & 15;
        uint4 v = *(const uint4*)&Ls[row * 136 + seg * 8];
        int gr = row0 + row;
        if (gr < NNODES)
            *(uint4*)(dst + (size_t)gr * 128 + seg * 8) = v;
    }
}

// ---------------------------------------------------------------------------
// gather_max: out[n,o] = elu(P[n,o] + max_valid_k Q[edge[n,k],o])  (ELU monotone)
// fp16 P/Q. 16 nodes/block, 16 thr/node, 8 halves (uint4) per thread.
// All 16 gathers issued first (MLP=16); masked k substitutes always-valid e[0].
// ---------------------------------------------------------------------------
__global__ __launch_bounds__(256) void gather_max(const unsigned short* __restrict__ Ph,
                                                  const unsigned short* __restrict__ Qh,
                                                  const int* __restrict__ edge,
                                                  float* __restrict__ out) {
    const int t  = threadIdx.x;
    const int n  = blockIdx.x * 16 + (t >> 4);   // 50000 = 16 * 3125
    const int o8 = (t & 15) * 8;

    const int4* er = (const int4*)(edge + n * KNEI);
    int4 e0 = er[0], e1 = er[1], e2 = er[2], e3 = er[3];
    int ia[16] = {e0.x, e0.y, e0.z, e0.w, e1.x, e1.y, e1.z, e1.w,
                  e2.x, e2.y, e2.z, e2.w, e3.x, e3.y, e3.z, e3.w};
    const int s0 = ia[0];                        // k=0 never masked
    const unsigned short* qb = Qh + o8;

    uint4 q[16];
    #pragma unroll
    for (int k = 0; k < 16; ++k) {
        int ix = ia[k] < 0 ? s0 : ia[k];
        q[k] = *(const uint4*)(qb + (size_t)ix * 128);
    }
    uint4 pv = *(const uint4*)(Ph + (size_t)n * 128 + o8);

    float2 m0 = h2f2(q[0].x), m1 = h2f2(q[0].y), m2 = h2f2(q[0].z), m3 = h2f2(q[0].w);
    #pragma unroll
    for (int k = 1; k < 16; ++k) {
        float2 a0 = h2f2(q[k].x), a1 = h2f2(q[k].y), a2 = h2f2(q[k].z), a3 = h2f2(q[k].w);
        m0.x = fmaxf(m0.x, a0.x); m0.y = fmaxf(m0.y, a0.y);
        m1.x = fmaxf(m1.x, a1.x); m1.y = fmaxf(m1.y, a1.y);
        m2.x = fmaxf(m2.x, a2.x); m2.y = fmaxf(m2.y, a2.y);
        m3.x = fmaxf(m3.x, a3.x); m3.y = fmaxf(m3.y, a3.y);
    }
    float2 p0 = h2f2(pv.x), p1 = h2f2(pv.y), p2 = h2f2(pv.z), p3 = h2f2(pv.w);

    float z[8] = {p0.x + m0.x, p0.y + m0.y, p1.x + m1.x, p1.y + m1.y,
                  p2.x + m2.x, p2.y + m2.y, p3.x + m3.x, p3.y + m3.y};
    float r[8];
    #pragma unroll
    for (int i = 0; i < 8; ++i) r[i] = z[i] > 0.f ? z[i] : expm1f(z[i]);

    float* ob = out + (size_t)n * 128 + o8;
    *(float4*)ob       = make_float4(r[0], r[1], r[2], r[3]);
    *(float4*)(ob + 4) = make_float4(r[4], r[5], r[6], r[7]);
}

extern "C" void kernel_launch(void* const* d_in, const int* in_sizes, int n_in,
                              void* d_out, int out_size, void* d_ws, size_t ws_size,
                              hipStream_t stream) {
    const float* x    = (const float*)d_in[0];
    const int*   edge = (const int*)d_in[1];
    const float* W    = (const float*)d_in[2];
    const float* bias = (const float*)d_in[3];
    float* out = (float*)d_out;

    unsigned short* Qh = (unsigned short*)d_ws;              // 12.8 MB
    unsigned short* Ph = Qh + 6400000;                       // 12.8 MB
    unsigned short* BT = Qh + 12800000;                      // 64 KB

    prep_bt<<<256, 128, 0, stream>>>(W, BT);
    gemm_bf16<<<dim3((NNODES + 63) / 64, 2), 256, 0, stream>>>(x, BT, bias, Ph, Qh);
    gather_max<<<NNODES / 16, 256, 0, stream>>>(Ph, Qh, edge, out);
}